// Round 2
// baseline (52.247 us; speedup 1.0000x reference)
//
#include <hip/hip_runtime.h>

// hidden_layers: (4, B, T, D) float32
// word_ids:      (B, T) int32, SORTED along T, values in [0, W] (W = NONE)
// output:        (B*(W+1), D) float32; row (b,0)=CLS = mean-over-layers of
//                token 0; row (b,1+w)=segment mean of layer-mean over tokens
//                with word_ids[b,t]==w (0 if empty segment).
#define NB 32
#define NT 512
#define ND 1024
#define NW 100
#define NL 4

// One wave (64 threads) per output row. Each thread accumulates 4 float4
// chunks (d = tid*4 + c*256), giving 16 independent global loads in flight
// per token. 3232 single-wave blocks are fully co-resident on 256 CUs
// (12.6 waves/CU of 32) -> no dispatch tail, max memory-level parallelism.
__global__ __launch_bounds__(64) void bert_word_pool_kernel(
    const float* __restrict__ hidden,   // (NL, NB, NT, ND)
    const int*   __restrict__ word_ids, // (NB, NT)
    float*       __restrict__ out)      // (NB*(NW+1), ND)
{
    const int row = blockIdx.x;          // 0 .. NB*(NW+1)-1
    const int b   = row / (NW + 1);
    const int j   = row - b * (NW + 1);  // 0 = cls, 1..NW = word (j-1)
    const int tid = threadIdx.x;         // 0..63

    const size_t layer_stride = (size_t)NB * NT * ND;
    const float* hb = hidden + (size_t)b * NT * ND;

    float4 acc[4];
    #pragma unroll
    for (int c = 0; c < 4; ++c) acc[c] = make_float4(0.f, 0.f, 0.f, 0.f);

    int start, count;
    if (j == 0) {
        start = 0; count = 1;            // CLS: token 0 only
    } else {
        const int w = j - 1;
        const int* ids = word_ids + b * NT;
        // lower_bound(w)
        int lo = 0, hi = NT;
        while (lo < hi) {
            int mid = (lo + hi) >> 1;
            if (ids[mid] < w) lo = mid + 1; else hi = mid;
        }
        start = lo;
        // lower_bound(w+1)
        hi = NT;
        while (lo < hi) {
            int mid = (lo + hi) >> 1;
            if (ids[mid] < w + 1) lo = mid + 1; else hi = mid;
        }
        count = lo - start;
    }

    for (int t = start; t < start + count; ++t) {
        const float* hp = hb + (size_t)t * ND + tid * 4;
        #pragma unroll
        for (int l = 0; l < NL; ++l) {
            const float* hpl = hp + (size_t)l * layer_stride;
            #pragma unroll
            for (int c = 0; c < 4; ++c) {
                const float4 v = *reinterpret_cast<const float4*>(hpl + c * 256);
                acc[c].x += v.x; acc[c].y += v.y; acc[c].z += v.z; acc[c].w += v.w;
            }
        }
    }

    const float scale = (count > 0) ? (1.0f / (float)(NL * count)) : 0.0f;
    float* op = out + (size_t)row * ND + tid * 4;
    #pragma unroll
    for (int c = 0; c < 4; ++c) {
        float4 r = make_float4(acc[c].x * scale, acc[c].y * scale,
                               acc[c].z * scale, acc[c].w * scale);
        *reinterpret_cast<float4*>(op + c * 256) = r;
    }
}

extern "C" void kernel_launch(void* const* d_in, const int* in_sizes, int n_in,
                              void* d_out, int out_size, void* d_ws, size_t ws_size,
                              hipStream_t stream) {
    const float* hidden   = (const float*)d_in[0];
    const int*   word_ids = (const int*)d_in[1];
    // d_in[2] = num_words scalar (==100), compiled in as NW.
    float* out = (float*)d_out;

    const int rows = NB * (NW + 1);   // 3232 blocks, 1 wave each
    bert_word_pool_kernel<<<rows, 64, 0, stream>>>(hidden, word_ids, out);
}